// Round 1
// baseline (243.783 us; speedup 1.0000x reference)
//
#include <hip/hip_runtime.h>
#include <math.h>

#define NANCH 896
#define MAXD 64
#define SLOTS 14   // 896 / 64

__device__ __forceinline__ float selv17(const float d[17], int c) {
    float v = d[0];
#pragma unroll
    for (int k = 1; k < 17; ++k) v = (c == k) ? d[k] : v;
    return v;
}

__global__ __launch_bounds__(256, 2) void blaze_kernel(
    const float* __restrict__ raw_boxes,   // [B,896,16]
    const float* __restrict__ raw_scores,  // [B,896]
    const float* __restrict__ anchors,     // [896,4]
    const float* __restrict__ tmat,        // [B,8]
    const int* __restrict__ hptr,
    const int* __restrict__ wptr,
    float* __restrict__ out)               // [B,64,17]
{
    __shared__ float scoords[NANCH * 16];  // compacted decoded coords, 16-float rows
    __shared__ float sscore[NANCH];        // compacted scores
    __shared__ int   wcnt[4];

    const int b    = blockIdx.x;
    const int tid  = threadIdx.x;
    const int lane = tid & 63;
    const int wv   = tid >> 6;

    const float* rb = raw_boxes  + (size_t)b * (NANCH * 16);
    const float* rs = raw_scores + (size_t)b * NANCH;

    // ---- Phase A: scores (4 independent loads up front) ----
    float sval[4];
    bool  act[4];
#pragma unroll
    for (int r = 0; r < 4; ++r) {
        int a = r * 256 + tid;
        float s = -1.f;
        if (a < NANCH) {
            float x = rs[a];
            x = fminf(fmaxf(x, -100.f), 100.f);
            s = 1.f / (1.f + expf(-x));   // x>=0 side is exact-safe; x<0 unused
        }
        sval[r] = s;
        act[r]  = (s >= 0.5f);
    }

    // ---- Phase B: decode only active anchors (saves ~half of raw_boxes fetch) ----
    float cc[4][16];
#pragma unroll
    for (int r = 0; r < 4; ++r) {
        int a = r * 256 + tid;
        if (act[r]) {
            float4 an = *(const float4*)(anchors + a * 4);
            float4 r0 = *(const float4*)(rb + a * 16);
            float4 r1 = *(const float4*)(rb + a * 16 + 4);
            float4 r2 = *(const float4*)(rb + a * 16 + 8);
            float4 r3 = *(const float4*)(rb + a * 16 + 12);
            float ax = an.x, ay = an.y, aw = an.z, ah = an.w;
            const float inv = 1.f / 128.f;
            float xc = r0.x * inv * aw + ax;
            float yc = r0.y * inv * ah + ay;
            float ww = r0.z * inv * aw;
            float hh = r0.w * inv * ah;
            cc[r][0] = yc - hh * 0.5f;   // ymin
            cc[r][1] = xc - ww * 0.5f;   // xmin
            cc[r][2] = yc + hh * 0.5f;   // ymax
            cc[r][3] = xc + ww * 0.5f;   // xmax
            float kx[6] = { r1.x, r1.z, r2.x, r2.z, r3.x, r3.z };
            float ky[6] = { r1.y, r1.w, r2.y, r2.w, r3.y, r3.w };
#pragma unroll
            for (int k = 0; k < 6; ++k) {
                cc[r][4 + 2 * k] = kx[k] * inv * aw + ax;
                cc[r][5 + 2 * k] = ky[k] * inv * ah + ay;
            }
        }
    }

    // ---- Phase C: ordered block-wide compaction into LDS ----
    int base = 0;
#pragma unroll
    for (int r = 0; r < 4; ++r) {
        unsigned long long mask = __ballot(act[r]);
        if (lane == 0) wcnt[wv] = __popcll(mask);
        __syncthreads();
        int off = base;
        for (int w2 = 0; w2 < wv; ++w2) off += wcnt[w2];
        int tot = wcnt[0] + wcnt[1] + wcnt[2] + wcnt[3];
        if (act[r]) {
            int pos = off + (int)__popcll(mask & ((1ull << lane) - 1ull));
            float4* dst = (float4*)(scoords + pos * 16);
            dst[0] = make_float4(cc[r][0],  cc[r][1],  cc[r][2],  cc[r][3]);
            dst[1] = make_float4(cc[r][4],  cc[r][5],  cc[r][6],  cc[r][7]);
            dst[2] = make_float4(cc[r][8],  cc[r][9],  cc[r][10], cc[r][11]);
            dst[3] = make_float4(cc[r][12], cc[r][13], cc[r][14], cc[r][15]);
            sscore[pos] = sval[r];
        }
        base += tot;
        __syncthreads();
    }
    const int count = base;

    if (wv != 0) return;   // no barriers past this point: wave 0 is wave-synchronous

    // ---- readback: wave 0 owns compacted slots i = lane + 64*j ----
    float rem[SLOTS], sc[SLOTS], b0[SLOTS], b1[SLOTS], b2[SLOTS], b3[SLOTS], ar[SLOTS];
#pragma unroll
    for (int j = 0; j < SLOTS; ++j) {
        int i = lane + 64 * j;
        if (i < count) {
            float4 bb = *(const float4*)(scoords + i * 16);
            b0[j] = bb.x; b1[j] = bb.y; b2[j] = bb.z; b3[j] = bb.w;
            float s = sscore[i];
            sc[j] = s; rem[j] = s;
            ar[j] = fmaxf(bb.z - bb.x, 0.f) * fmaxf(bb.w - bb.y, 0.f);
        } else {
            rem[j] = -1.f; sc[j] = 0.f;
            b0[j] = b1[j] = b2[j] = b3[j] = 0.f; ar[j] = 0.f;
        }
    }

    const float* M = tmat + (size_t)b * 8;
    const float m0 = M[0], m1 = M[1], m3 = M[3];
    const float m4 = M[4], m5 = M[5], m7 = M[7];
    const float hf = (float)(*hptr);
    const float wf = (float)(*wptr);
    float* ob = out + (size_t)b * (MAXD * 17);

    int iter = 0;
    while (true) {
        // argmax(rem), first-index tie-break
        float bv = -2.f; int bi = 1 << 30;
#pragma unroll
        for (int j = 0; j < SLOTS; ++j) {
            if (rem[j] > bv) { bv = rem[j]; bi = lane + 64 * j; }
        }
#pragma unroll
        for (int s2 = 32; s2 >= 1; s2 >>= 1) {
            float ov = __shfl_xor(bv, s2, 64);
            int   oi = __shfl_xor(bi, s2, 64);
            if (ov > bv || (ov == bv && oi < bi)) { bv = ov; bi = oi; }
        }

        if (bv <= 0.f) {
            // all remaining dets are zeros — fixed point
            int n = (MAXD - iter) * 17;
            int bo = iter * 17;
            for (int e = lane; e < n; e += 64) ob[bo + e] = 0.f;
            break;
        }

        // best box (broadcast LDS read; bi is wave-uniform)
        float4 bb = *(const float4*)(scoords + bi * 16);
        float a1 = fmaxf(bb.z - bb.x, 0.f) * fmaxf(bb.w - bb.y, 0.f);

        float acc[16];
#pragma unroll
        for (int c = 0; c < 16; ++c) acc[c] = 0.f;
        float wsum = 0.f;
        bool anyov = false;

#pragma unroll
        for (int j = 0; j < SLOTS; ++j) {
            int i = lane + 64 * j;
            bool valid = (i < count) && (rem[j] > 0.f);
            if (valid) {
                float yA = fmaxf(bb.x, b0[j]);
                float xA = fmaxf(bb.y, b1[j]);
                float yB = fminf(bb.z, b2[j]);
                float xB = fminf(bb.w, b3[j]);
                float inter = fmaxf(yB - yA, 0.f) * fmaxf(xB - xA, 0.f);
                float iou = inter / fmaxf(a1 + ar[j] - inter, 1e-6f);
                if (iou > 0.3f) {
                    anyov = true;
                    float wj = sc[j];
                    rem[j] = -1.f;
                    wsum += wj;
                    const float4* cp = (const float4*)(scoords + i * 16);
                    float4 c0 = cp[0], c1 = cp[1], c2 = cp[2], c3 = cp[3];
                    acc[0]  += c0.x * wj; acc[1]  += c0.y * wj;
                    acc[2]  += c0.z * wj; acc[3]  += c0.w * wj;
                    acc[4]  += c1.x * wj; acc[5]  += c1.y * wj;
                    acc[6]  += c1.z * wj; acc[7]  += c1.w * wj;
                    acc[8]  += c2.x * wj; acc[9]  += c2.y * wj;
                    acc[10] += c2.z * wj; acc[11] += c2.w * wj;
                    acc[12] += c3.x * wj; acc[13] += c3.y * wj;
                    acc[14] += c3.z * wj; acc[15] += c3.w * wj;
                }
            }
        }

        bool stuck = (__ballot(anyov) == 0ull);  // nothing removed -> fixed point

        float det[17];
        if (!stuck) {
#pragma unroll
            for (int s2 = 32; s2 >= 1; s2 >>= 1) {
                wsum += __shfl_xor(wsum, s2, 64);
#pragma unroll
                for (int c = 0; c < 16; ++c) acc[c] += __shfl_xor(acc[c], s2, 64);
            }
            float dnm = fmaxf(wsum, 1e-6f);
#pragma unroll
            for (int c = 0; c < 16; ++c) det[c] = acc[c] / dnm;
        } else {
#pragma unroll
            for (int c = 0; c < 16; ++c) det[c] = 0.f;
        }
        det[16] = bv;

        // project + rescale (valid: bv > 0 here). pairs (x_idx, y_idx)
        {
            const int xi[8] = { 1, 3, 4, 6, 8, 10, 12, 14 };
            const int yi[8] = { 0, 2, 5, 7, 9, 11, 13, 15 };
#pragma unroll
            for (int k = 0; k < 8; ++k) {
                float x = det[xi[k]], y = det[yi[k]];
                det[xi[k]] = (x * m0 + y * m1 + m3) * wf;
                det[yi[k]] = (x * m4 + y * m5 + m7) * hf;
            }
        }

        if (stuck) {
            // every remaining iteration emits this same det
            int n = (MAXD - iter) * 17;
            int bo = iter * 17;
            for (int e = lane; e < n; e += 64) {
                int c = e % 17;
                ob[bo + e] = selv17(det, c);
            }
            break;
        } else {
            if (lane < 17) ob[iter * 17 + lane] = selv17(det, lane);
            ++iter;
            if (iter == MAXD) break;
        }
    }
}

extern "C" void kernel_launch(void* const* d_in, const int* in_sizes, int n_in,
                              void* d_out, int out_size, void* d_ws, size_t ws_size,
                              hipStream_t stream) {
    (void)n_in; (void)out_size; (void)d_ws; (void)ws_size;
    const float* raw_boxes  = (const float*)d_in[0];
    const float* raw_scores = (const float*)d_in[1];
    const float* anchors    = (const float*)d_in[2];
    const float* tmat       = (const float*)d_in[3];
    const int*   hptr       = (const int*)d_in[4];
    const int*   wptr       = (const int*)d_in[5];
    float* out = (float*)d_out;

    const int B = in_sizes[0] / (NANCH * 16);
    blaze_kernel<<<B, 256, 0, stream>>>(raw_boxes, raw_scores, anchors, tmat,
                                        hptr, wptr, out);
}

// Round 2
// 219.247 us; speedup vs baseline: 1.1119x; 1.1119x over previous
//
#include <hip/hip_runtime.h>
#include <math.h>

#define NANCH 896
#define MAXD 64
#define MAXSLOTS 14   // 896 / 64

__device__ __forceinline__ float selv17(const float d[17], int c) {
    float v = d[0];
#pragma unroll
    for (int k = 1; k < 17; ++k) v = (c == k) ? d[k] : v;
    return v;
}

__global__ __launch_bounds__(256, 2) void blaze_kernel(
    const float* __restrict__ raw_boxes,   // [B,896,16]
    const float* __restrict__ raw_scores,  // [B,896]
    const float* __restrict__ anchors,     // [896,4]
    const float* __restrict__ tmat,        // [B,8]
    const int* __restrict__ hptr,
    const int* __restrict__ wptr,
    float* __restrict__ out)               // [B,64,17]
{
    __shared__ float scoords[NANCH * 16];  // compacted decoded coords, 16-float rows
    __shared__ float sscore[NANCH];        // compacted scores
    __shared__ int   wcnt[16];             // [r][wave]
    __shared__ float sdet[17];

    const int b    = blockIdx.x;
    const int tid  = threadIdx.x;
    const int lane = tid & 63;
    const int wv   = tid >> 6;

    const float* rb = raw_boxes  + (size_t)b * (NANCH * 16);
    const float* rs = raw_scores + (size_t)b * NANCH;

    // ---- Phase A: scores, ballots, compaction offsets (light registers only) ----
    float sval[4];
    bool  act[4];
#pragma unroll
    for (int r = 0; r < 4; ++r) {
        int a = r * 256 + tid;
        float s = -1.f;
        if (a < NANCH) {
            float x = rs[a];
            x = fminf(fmaxf(x, -100.f), 100.f);
            s = 1.f / (1.f + expf(-x));   // only x>=0 side is consumed downstream
        }
        sval[r] = s;
        act[r]  = (s >= 0.5f);
    }
    unsigned long long bm[4];
#pragma unroll
    for (int r = 0; r < 4; ++r) {
        bm[r] = __ballot(act[r]);
        if (lane == 0) wcnt[r * 4 + wv] = __popcll(bm[r]);
    }
    __syncthreads();
    int pos[4];
    int base = 0;
#pragma unroll
    for (int r = 0; r < 4; ++r) {
        int off = base;
        for (int w2 = 0; w2 < wv; ++w2) off += wcnt[r * 4 + w2];
        pos[r] = off + (int)__popcll(bm[r] & ((1ull << lane) - 1ull));
        base += wcnt[r * 4 + 0] + wcnt[r * 4 + 1] + wcnt[r * 4 + 2] + wcnt[r * 4 + 3];
    }
    const int count = base;

    // ---- Phase B: gated load -> decode -> LDS store; short live ranges, no barrier inside ----
#pragma unroll
    for (int r = 0; r < 4; ++r) {
        int a = r * 256 + tid;
        if (act[r]) {
            float4 an = *(const float4*)(anchors + a * 4);
            float4 r0 = *(const float4*)(rb + a * 16);
            float4 r1 = *(const float4*)(rb + a * 16 + 4);
            float4 r2 = *(const float4*)(rb + a * 16 + 8);
            float4 r3 = *(const float4*)(rb + a * 16 + 12);
            float ax = an.x, ay = an.y, aw = an.z, ah = an.w;
            const float inv = 1.f / 128.f;
            float xc = r0.x * inv * aw + ax;
            float yc = r0.y * inv * ah + ay;
            float ww = r0.z * inv * aw;
            float hh = r0.w * inv * ah;
            float4* dst = (float4*)(scoords + pos[r] * 16);
            dst[0] = make_float4(yc - hh * 0.5f, xc - ww * 0.5f,
                                 yc + hh * 0.5f, xc + ww * 0.5f);
            dst[1] = make_float4(r1.x * inv * aw + ax, r1.y * inv * ah + ay,
                                 r1.z * inv * aw + ax, r1.w * inv * ah + ay);
            dst[2] = make_float4(r2.x * inv * aw + ax, r2.y * inv * ah + ay,
                                 r2.z * inv * aw + ax, r2.w * inv * ah + ay);
            dst[3] = make_float4(r3.x * inv * aw + ax, r3.y * inv * ah + ay,
                                 r3.z * inv * aw + ax, r3.w * inv * ah + ay);
            sscore[pos[r]] = sval[r];
        }
    }
    __syncthreads();

    if (wv != 0) return;   // wave 0 only beyond here; wave-synchronous, no barriers

    // ---- NMS state: only rem[] lives in registers (static indexing throughout) ----
    float rem[MAXSLOTS];
#pragma unroll
    for (int j = 0; j < MAXSLOTS; ++j) {
        int i = lane + 64 * j;
        float v = -1.f;
        if (i < count) v = sscore[i];
        rem[j] = v;
    }

    const float* M = tmat + (size_t)b * 8;
    const float m0 = M[0], m1 = M[1], m3 = M[3];
    const float m4 = M[4], m5 = M[5], m7 = M[7];
    const float hf = (float)(*hptr);
    const float wf = (float)(*wptr);
    float* ob = out + (size_t)b * (MAXD * 17);

    int iter = 0;
    while (true) {
        // argmax(rem), first-index tie-break
        float bv = -2.f; int bi = 1 << 30;
#pragma unroll
        for (int j = 0; j < MAXSLOTS; ++j) {
            if (64 * j < count) {
                if (rem[j] > bv) { bv = rem[j]; bi = lane + 64 * j; }
            }
        }
#pragma unroll
        for (int s2 = 32; s2 >= 1; s2 >>= 1) {
            float ov = __shfl_xor(bv, s2, 64);
            int   oi = __shfl_xor(bi, s2, 64);
            if (ov > bv || (ov == bv && oi < bi)) { bv = ov; bi = oi; }
        }

        if (bv <= 0.f) {
            // all remaining dets are zeros — fixed point
            int n = (MAXD - iter) * 17;
            float* op = ob + iter * 17;
            for (int e = lane; e < n; e += 64) op[e] = 0.f;
            break;
        }

        // best box (bi is wave-uniform -> broadcast LDS read)
        float4 bb = *(const float4*)(scoords + bi * 16);
        float a1 = fmaxf(bb.z - bb.x, 0.f) * fmaxf(bb.w - bb.y, 0.f);

        float acc[16];
#pragma unroll
        for (int c = 0; c < 16; ++c) acc[c] = 0.f;
        float wsum = 0.f;
        bool anyov = false;

#pragma unroll
        for (int j = 0; j < MAXSLOTS; ++j) {
            if (64 * j < count) {
                int i = lane + 64 * j;
                bool valid = (i < count) && (rem[j] > 0.f);
                if (valid) {
                    const float4* cp = (const float4*)(scoords + i * 16);
                    float4 c0 = cp[0];
                    float ai = fmaxf(c0.z - c0.x, 0.f) * fmaxf(c0.w - c0.y, 0.f);
                    float yA = fmaxf(bb.x, c0.x);
                    float xA = fmaxf(bb.y, c0.y);
                    float yB = fminf(bb.z, c0.z);
                    float xB = fminf(bb.w, c0.w);
                    float inter = fmaxf(yB - yA, 0.f) * fmaxf(xB - xA, 0.f);
                    float iou = inter / fmaxf(a1 + ai - inter, 1e-6f);
                    if (iou > 0.3f) {
                        anyov = true;
                        float wj = sscore[i];
                        rem[j] = -1.f;
                        wsum += wj;
                        float4 c1 = cp[1], c2 = cp[2], c3 = cp[3];
                        acc[0]  += c0.x * wj; acc[1]  += c0.y * wj;
                        acc[2]  += c0.z * wj; acc[3]  += c0.w * wj;
                        acc[4]  += c1.x * wj; acc[5]  += c1.y * wj;
                        acc[6]  += c1.z * wj; acc[7]  += c1.w * wj;
                        acc[8]  += c2.x * wj; acc[9]  += c2.y * wj;
                        acc[10] += c2.z * wj; acc[11] += c2.w * wj;
                        acc[12] += c3.x * wj; acc[13] += c3.y * wj;
                        acc[14] += c3.z * wj; acc[15] += c3.w * wj;
                    }
                }
            }
        }

        bool stuck = (__ballot(anyov) == 0ull);  // nothing removed -> fixed point

        float det[17];
        if (!stuck) {
#pragma unroll
            for (int s2 = 32; s2 >= 1; s2 >>= 1) {
                wsum += __shfl_xor(wsum, s2, 64);
#pragma unroll
                for (int c = 0; c < 16; ++c) acc[c] += __shfl_xor(acc[c], s2, 64);
            }
            float dnm = fmaxf(wsum, 1e-6f);
#pragma unroll
            for (int c = 0; c < 16; ++c) det[c] = acc[c] / dnm;
        } else {
#pragma unroll
            for (int c = 0; c < 16; ++c) det[c] = 0.f;
        }
        det[16] = bv;

        // project + rescale
        {
            const int xi[8] = { 1, 3, 4, 6, 8, 10, 12, 14 };
            const int yi[8] = { 0, 2, 5, 7, 9, 11, 13, 15 };
#pragma unroll
            for (int k = 0; k < 8; ++k) {
                float x = det[xi[k]], y = det[yi[k]];
                det[xi[k]] = (x * m0 + y * m1 + m3) * wf;
                det[yi[k]] = (x * m4 + y * m5 + m7) * hf;
            }
        }

        if (stuck) {
            // every remaining iteration emits this same det — stage in LDS, fill
            if (lane < 17) sdet[lane] = selv17(det, lane);
            int n = (MAXD - iter) * 17;
            float* op = ob + iter * 17;
            for (int e = lane; e < n; e += 64) {
                int c = e % 17;
                op[e] = sdet[c];
            }
            break;
        } else {
            if (lane < 17) ob[iter * 17 + lane] = selv17(det, lane);
            ++iter;
            if (iter == MAXD) break;
        }
    }
}

extern "C" void kernel_launch(void* const* d_in, const int* in_sizes, int n_in,
                              void* d_out, int out_size, void* d_ws, size_t ws_size,
                              hipStream_t stream) {
    (void)n_in; (void)out_size; (void)d_ws; (void)ws_size;
    const float* raw_boxes  = (const float*)d_in[0];
    const float* raw_scores = (const float*)d_in[1];
    const float* anchors    = (const float*)d_in[2];
    const float* tmat       = (const float*)d_in[3];
    const int*   hptr       = (const int*)d_in[4];
    const int*   wptr       = (const int*)d_in[5];
    float* out = (float*)d_out;

    const int B = in_sizes[0] / (NANCH * 16);
    blaze_kernel<<<B, 256, 0, stream>>>(raw_boxes, raw_scores, anchors, tmat,
                                        hptr, wptr, out);
}

// Round 3
// 203.098 us; speedup vs baseline: 1.2003x; 1.0795x over previous
//
#include <hip/hip_runtime.h>
#include <math.h>

#define NANCH 896
#define MAXD 64
#define MAXSLOTS 14   // 896 / 64

__device__ __forceinline__ float selv17(const float d[17], int c) {
    float v = d[0];
#pragma unroll
    for (int k = 1; k < 17; ++k) v = (c == k) ? d[k] : v;
    return v;
}

__global__ __launch_bounds__(256, 5) void blaze_kernel(
    const float* __restrict__ raw_boxes,   // [B,896,16]
    const float* __restrict__ raw_scores,  // [B,896]
    const float* __restrict__ anchors,     // [896,4]
    const float* __restrict__ tmat,        // [B,8]
    const int* __restrict__ hptr,
    const int* __restrict__ wptr,
    float* __restrict__ out)               // [B,64,17]
{
    // ~21.6 KB total -> 5+ blocks/CU (vs 78.8 KB -> 2 blocks/CU before)
    __shared__ float4 sbox[NANCH];   // compacted decoded box (ymin,xmin,ymax,xmax)
    __shared__ float  sscore[NANCH]; // compacted sigmoid score
    __shared__ int    sidx[NANCH];   // compacted -> original anchor index
    __shared__ int    wcnt[16];      // [r][wave]
    __shared__ float  sdet[17];

    const int b    = blockIdx.x;
    const int tid  = threadIdx.x;
    const int lane = tid & 63;
    const int wv   = tid >> 6;

    const float* rb = raw_boxes  + (size_t)b * (NANCH * 16);
    const float* rs = raw_scores + (size_t)b * NANCH;
    const float inv = 1.f / 128.f;

    // ---- Phase A: scores, ballots, compaction offsets ----
    float sval[4];
    bool  act[4];
#pragma unroll
    for (int r = 0; r < 4; ++r) {
        int a = r * 256 + tid;
        float s = -1.f;
        if (a < NANCH) {
            float x = rs[a];
            x = fminf(fmaxf(x, -100.f), 100.f);
            s = 1.f / (1.f + expf(-x));   // only x>=0 side is consumed downstream
        }
        sval[r] = s;
        act[r]  = (s >= 0.5f);
    }
    unsigned long long bm[4];
#pragma unroll
    for (int r = 0; r < 4; ++r) {
        bm[r] = __ballot(act[r]);
        if (lane == 0) wcnt[r * 4 + wv] = __popcll(bm[r]);
    }
    __syncthreads();
    int pos[4];
    int base = 0;
#pragma unroll
    for (int r = 0; r < 4; ++r) {
        int off = base;
        for (int w2 = 0; w2 < wv; ++w2) off += wcnt[r * 4 + w2];
        pos[r] = off + (int)__popcll(bm[r] & ((1ull << lane) - 1ull));
        base += wcnt[r * 4 + 0] + wcnt[r * 4 + 1] + wcnt[r * 4 + 2] + wcnt[r * 4 + 3];
    }
    const int count = base;

    // ---- Phase B: gated load -> box decode -> LDS store (boxes only) ----
#pragma unroll
    for (int r = 0; r < 4; ++r) {
        int a = r * 256 + tid;
        if (act[r]) {
            float4 an = *(const float4*)(anchors + a * 4);
            float4 r0 = *(const float4*)(rb + a * 16);   // fetches the 64B row line
            float xc = r0.x * inv * an.z + an.x;
            float yc = r0.y * inv * an.w + an.y;
            float ww = r0.z * inv * an.z;
            float hh = r0.w * inv * an.w;
            sbox[pos[r]] = make_float4(yc - hh * 0.5f, xc - ww * 0.5f,
                                       yc + hh * 0.5f, xc + ww * 0.5f);
            sscore[pos[r]] = sval[r];
            sidx[pos[r]]   = a;
        }
    }
    __syncthreads();

    if (wv != 0) return;   // wave 0 only beyond here; wave-synchronous, no barriers

    // ---- NMS state: only rem[] in registers (static indexing) ----
    float rem[MAXSLOTS];
#pragma unroll
    for (int j = 0; j < MAXSLOTS; ++j) {
        int i = lane + 64 * j;
        rem[j] = (i < count) ? sscore[i] : -1.f;
    }

    const float* M = tmat + (size_t)b * 8;
    const float m0 = M[0], m1 = M[1], m3 = M[3];
    const float m4 = M[4], m5 = M[5], m7 = M[7];
    const float hf = (float)(*hptr);
    const float wf = (float)(*wptr);
    float* ob = out + (size_t)b * (MAXD * 17);

    int iter = 0;
    while (true) {
        // argmax(rem), first-index tie-break
        float bv = -2.f; int bi = 1 << 30;
#pragma unroll
        for (int j = 0; j < MAXSLOTS; ++j) {
            if (64 * j < count) {
                if (rem[j] > bv) { bv = rem[j]; bi = lane + 64 * j; }
            }
        }
#pragma unroll
        for (int s2 = 32; s2 >= 1; s2 >>= 1) {
            float ov = __shfl_xor(bv, s2, 64);
            int   oi = __shfl_xor(bi, s2, 64);
            if (ov > bv || (ov == bv && oi < bi)) { bv = ov; bi = oi; }
        }

        if (bv <= 0.f) {
            int n = (MAXD - iter) * 17;
            float* op = ob + iter * 17;
            for (int e = lane; e < n; e += 64) op[e] = 0.f;
            break;
        }

        float4 bb = sbox[bi];   // wave-uniform broadcast read
        float a1 = fmaxf(bb.z - bb.x, 0.f) * fmaxf(bb.w - bb.y, 0.f);

        float acc[16];
#pragma unroll
        for (int c = 0; c < 16; ++c) acc[c] = 0.f;
        float wsum = 0.f;
        bool anyov = false;

#pragma unroll
        for (int j = 0; j < MAXSLOTS; ++j) {
            if (64 * j < count) {
                int i = lane + 64 * j;
                bool valid = (i < count) && (rem[j] > 0.f);
                if (valid) {
                    float4 c0 = sbox[i];
                    float ai = fmaxf(c0.z - c0.x, 0.f) * fmaxf(c0.w - c0.y, 0.f);
                    float yA = fmaxf(bb.x, c0.x);
                    float xA = fmaxf(bb.y, c0.y);
                    float yB = fminf(bb.z, c0.z);
                    float xB = fminf(bb.w, c0.w);
                    float inter = fmaxf(yB - yA, 0.f) * fmaxf(xB - xA, 0.f);
                    float iou = inter / fmaxf(a1 + ai - inter, 1e-6f);
                    if (iou > 0.3f) {
                        anyov = true;
                        float wj = sscore[i];
                        rem[j] = -1.f;
                        wsum += wj;
                        acc[0] += c0.x * wj; acc[1] += c0.y * wj;
                        acc[2] += c0.z * wj; acc[3] += c0.w * wj;
                        // recompute keypoint decode from global (L1/L2-hot line)
                        int a = sidx[i];
                        float4 an = *(const float4*)(anchors + a * 4);
                        const float* rp = rb + a * 16;
                        float4 r1 = *(const float4*)(rp + 4);
                        float4 r2 = *(const float4*)(rp + 8);
                        float4 r3 = *(const float4*)(rp + 12);
                        acc[4]  += (r1.x * inv * an.z + an.x) * wj;
                        acc[5]  += (r1.y * inv * an.w + an.y) * wj;
                        acc[6]  += (r1.z * inv * an.z + an.x) * wj;
                        acc[7]  += (r1.w * inv * an.w + an.y) * wj;
                        acc[8]  += (r2.x * inv * an.z + an.x) * wj;
                        acc[9]  += (r2.y * inv * an.w + an.y) * wj;
                        acc[10] += (r2.z * inv * an.z + an.x) * wj;
                        acc[11] += (r2.w * inv * an.w + an.y) * wj;
                        acc[12] += (r3.x * inv * an.z + an.x) * wj;
                        acc[13] += (r3.y * inv * an.w + an.y) * wj;
                        acc[14] += (r3.z * inv * an.z + an.x) * wj;
                        acc[15] += (r3.w * inv * an.w + an.y) * wj;
                    }
                }
            }
        }

        bool stuck = (__ballot(anyov) == 0ull);  // nothing removed -> fixed point

        float det[17];
        if (!stuck) {
#pragma unroll
            for (int s2 = 32; s2 >= 1; s2 >>= 1) {
                wsum += __shfl_xor(wsum, s2, 64);
#pragma unroll
                for (int c = 0; c < 16; ++c) acc[c] += __shfl_xor(acc[c], s2, 64);
            }
            float dnm = fmaxf(wsum, 1e-6f);
#pragma unroll
            for (int c = 0; c < 16; ++c) det[c] = acc[c] / dnm;
        } else {
#pragma unroll
            for (int c = 0; c < 16; ++c) det[c] = 0.f;
        }
        det[16] = bv;

        // project + rescale
        {
            const int xi[8] = { 1, 3, 4, 6, 8, 10, 12, 14 };
            const int yi[8] = { 0, 2, 5, 7, 9, 11, 13, 15 };
#pragma unroll
            for (int k = 0; k < 8; ++k) {
                float x = det[xi[k]], y = det[yi[k]];
                det[xi[k]] = (x * m0 + y * m1 + m3) * wf;
                det[yi[k]] = (x * m4 + y * m5 + m7) * hf;
            }
        }

        if (stuck) {
            if (lane < 17) sdet[lane] = selv17(det, lane);
            int n = (MAXD - iter) * 17;
            float* op = ob + iter * 17;
            for (int e = lane; e < n; e += 64) {
                int c = e % 17;
                op[e] = sdet[c];
            }
            break;
        } else {
            if (lane < 17) ob[iter * 17 + lane] = selv17(det, lane);
            ++iter;
            if (iter == MAXD) break;
        }
    }
}

extern "C" void kernel_launch(void* const* d_in, const int* in_sizes, int n_in,
                              void* d_out, int out_size, void* d_ws, size_t ws_size,
                              hipStream_t stream) {
    (void)n_in; (void)out_size; (void)d_ws; (void)ws_size;
    const float* raw_boxes  = (const float*)d_in[0];
    const float* raw_scores = (const float*)d_in[1];
    const float* anchors    = (const float*)d_in[2];
    const float* tmat       = (const float*)d_in[3];
    const int*   hptr       = (const int*)d_in[4];
    const int*   wptr       = (const int*)d_in[5];
    float* out = (float*)d_out;

    const int B = in_sizes[0] / (NANCH * 16);
    blaze_kernel<<<B, 256, 0, stream>>>(raw_boxes, raw_scores, anchors, tmat,
                                        hptr, wptr, out);
}